// Round 8
// baseline (135.599 us; speedup 1.0000x reference)
//
#include <hip/hip_runtime.h>
#include <hip/hip_bf16.h>

#define N_NODES 100000
#define N_EDGES 1600000
#define HEADS 8
#define NH (N_NODES * HEADS)    // 800000
#define ALPHA 0.2f

#define BSHIFT 7
#define BSIZE 128               // dst nodes per bucket
#define NBUCK 782               // ceil(100000 / 128)
#define EPB 4096                // edges per hist/scatter block
#define NEB 391                 // ceil(1600000 / 4096)
#define GPROJ 782               // ceil(800000 / 1024) proj blocks (1024 thr)
#define CAP 3072                // per-chunk record capacity (mean 2046, +22 sigma)
#define RPT 6                   // CAP / 512 records per thread

typedef float floatx2 __attribute__((ext_vector_type(2)));

__device__ __forceinline__ float lrelu(float s) {
    return s >= 0.0f ? s : ALPHA * s;
}

// Kernel 1 (fused): blocks [0, GPROJ) compute per-node projections
// p1[n*8+h], p2[n*8+h]; blocks [GPROJ, GPROJ+NEB) histogram dst buckets.
__global__ __launch_bounds__(1024) void proj_hist_kernel(
        const float* __restrict__ x, const float* __restrict__ a,
        const int* __restrict__ edge,
        float* __restrict__ p1, float* __restrict__ p2,
        unsigned* __restrict__ gcount) {
    __shared__ unsigned lh[NBUCK];
    int tid = threadIdx.x;
    if (blockIdx.x < GPROJ) {
        int t = blockIdx.x * 1024 + tid;
        if (t >= NH) return;
        int hd = t & 7;
        int n  = t >> 3;
        const float4* xp  = (const float4*)(x + (size_t)n * 128 + hd * 16);
        const float4* a1p = (const float4*)(a);
        const float4* a2p = (const float4*)(a + 16);
        float s1 = 0.f, s2 = 0.f;
#pragma unroll
        for (int i = 0; i < 4; ++i) {
            float4 xv = xp[i];
            float4 v1 = a1p[i];
            float4 v2 = a2p[i];
            s1 += xv.x * v1.x + xv.y * v1.y + xv.z * v1.z + xv.w * v1.w;
            s2 += xv.x * v2.x + xv.y * v2.y + xv.z * v2.z + xv.w * v2.w;
        }
        p1[t] = s1;
        p2[t] = s2;
    } else {
        for (int i = tid; i < NBUCK; i += 1024) lh[i] = 0;
        __syncthreads();
        int base = (blockIdx.x - GPROJ) * EPB;
#pragma unroll
        for (int k = 0; k < EPB / 1024; ++k) {
            int e = base + k * 1024 + tid;
            if (e < N_EDGES) atomicAdd(&lh[(unsigned)edge[N_EDGES + e] >> BSHIFT], 1u);
        }
        __syncthreads();
        for (int i = tid; i < NBUCK; i += 1024)
            if (lh[i]) atomicAdd(&gcount[i], lh[i]);
    }
}

// Kernel 2: exclusive scan of 782 bucket counts (single block).
__global__ __launch_bounds__(1024) void scan_kernel(const unsigned* __restrict__ gcount,
                                                    unsigned* __restrict__ goff,
                                                    unsigned* __restrict__ gcur) {
    __shared__ unsigned s[1024];
    int t = threadIdx.x;
    unsigned v = (t < NBUCK) ? gcount[t] : 0u;
    s[t] = v;
    __syncthreads();
    for (int d = 1; d < 1024; d <<= 1) {
        unsigned add = (t >= d) ? s[t - d] : 0u;
        __syncthreads();
        s[t] += add;
        __syncthreads();
    }
    if (t < NBUCK) {
        unsigned excl = s[t] - v;
        goff[t] = excl;
        gcur[t] = excl;
    }
    if (t == 0) goff[NBUCK] = N_EDGES;
}

// Kernel 3: scatter 8-byte records (eid<<24 | src<<7 | dst_local) into
// bucket-sorted order.
__global__ __launch_bounds__(1024) void scatter_kernel(const int* __restrict__ edge,
                                                       unsigned* __restrict__ gcur,
                                                       unsigned long long* __restrict__ sorted) {
    __shared__ int lsrc[EPB];
    __shared__ int ldst[EPB];
    __shared__ unsigned lh[NBUCK];
    __shared__ unsigned lbase[NBUCK];
    int t = threadIdx.x;
    int base = blockIdx.x * EPB;
    for (int i = t; i < NBUCK; i += 1024) lh[i] = 0;
    __syncthreads();
#pragma unroll
    for (int k = 0; k < EPB / 1024; ++k) {
        int i = k * 1024 + t, e = base + i;
        if (e < N_EDGES) {
            lsrc[i] = edge[e];
            int d = edge[N_EDGES + e];
            ldst[i] = d;
            atomicAdd(&lh[(unsigned)d >> BSHIFT], 1u);
        }
    }
    __syncthreads();
    for (int i = t; i < NBUCK; i += 1024) {
        unsigned c = lh[i];
        lbase[i] = c ? atomicAdd(&gcur[i], c) : 0u;
        lh[i] = 0;   // reuse as local cursor
    }
    __syncthreads();
#pragma unroll
    for (int k = 0; k < EPB / 1024; ++k) {
        int i = k * 1024 + t, e = base + i;
        if (e < N_EDGES) {
            int d = ldst[i];
            unsigned b = (unsigned)d >> BSHIFT;
            unsigned pos = lbase[b] + atomicAdd(&lh[b], 1u);
            sorted[pos] = ((unsigned long long)(unsigned)e << 24)
                        | ((unsigned)lsrc[i] << BSHIFT)
                        | (unsigned)(d & (BSIZE - 1));
        }
    }
}

// Kernel 4 (fused denom+norm): one block per bucket, no float atomics.
// Counting-sort records by dst_local in LDS; each thread owns (dl, head-pair).
// Pass 1: accumulate denominators in registers. Pass 2: re-walk LDS-resident
// records, recompute exp, scale by register-held reciprocal, write out[eid].
// Eliminates the separate norm kernel's edge re-read and p2/rd gathers; the
// only remaining random gather (p1, 3.2 MB) fits per-XCD L2.
__global__ __launch_bounds__(512) void fused_kernel(const unsigned long long* __restrict__ sorted,
                                                    const unsigned* __restrict__ goff,
                                                    const float* __restrict__ p1,
                                                    const float* __restrict__ p2,
                                                    float* __restrict__ out) {
    __shared__ unsigned lsrc[CAP];     // 12 KB sorted-by-dl src indices
    __shared__ unsigned leid[CAP];     // 12 KB sorted-by-dl edge ids
    __shared__ unsigned lh[BSIZE];     // per-dl count
    __shared__ unsigned lst[BSIZE];    // per-dl start
    __shared__ unsigned lcur[BSIZE];   // per-dl cursor
    __shared__ unsigned lscan[BSIZE];  // scan temp
    int t = threadIdx.x;
    int b = blockIdx.x;
    int dl = t >> 2;                   // 0..127: owned dst-local
    int hp = t & 3;                    // 0..3: owned head pair (2*hp, 2*hp+1)
    size_t node = (size_t)b * BSIZE + dl;
    bool valid = node < N_NODES;
    float p2a = 0.f, p2b = 0.f;
    if (valid) {
        float2 pv = *(const float2*)(p2 + node * 8 + hp * 2);
        p2a = pv.x; p2b = pv.y;
    }
    unsigned s0 = goff[b], s1 = goff[b + 1];
    unsigned nch = (s1 - s0 + CAP - 1) / CAP;   // 1 except pathological buckets

    // counting-sort one chunk of records into lsrc/leid (ordered by dl)
    auto sort_chunk = [&](unsigned c) {
        unsigned cs = s0 + c * CAP;
        unsigned cnt = min((unsigned)CAP, s1 - cs);
        __syncthreads();               // protect prior lsrc/leid readers
        if (t < BSIZE) lh[t] = 0;
        __syncthreads();
        unsigned long long recs[RPT];
#pragma unroll
        for (int k = 0; k < RPT; ++k) {
            unsigned i = (unsigned)t + (unsigned)k * 512u;
            bool v = i < cnt;
            recs[k] = v ? sorted[cs + i] : ~0ULL;
            if (v) atomicAdd(&lh[(unsigned)recs[k] & (BSIZE - 1)], 1u);
        }
        __syncthreads();
        if (t < BSIZE) lscan[t] = lh[t];
        __syncthreads();
        for (int d = 1; d < BSIZE; d <<= 1) {
            unsigned v = 0;
            if (t < BSIZE && t >= d) v = lscan[t - d];
            __syncthreads();
            if (t < BSIZE) lscan[t] += v;
            __syncthreads();
        }
        if (t < BSIZE) {
            unsigned st = lscan[t] - lh[t];
            lst[t] = st;
            lcur[t] = st;
        }
        __syncthreads();
#pragma unroll
        for (int k = 0; k < RPT; ++k) {
            if (recs[k] != ~0ULL) {
                unsigned lo = (unsigned)recs[k];
                unsigned d = lo & (BSIZE - 1);
                unsigned pos = atomicAdd(&lcur[d], 1u);
                lsrc[pos] = (lo >> BSHIFT) & 0x1FFFFu;
                leid[pos] = (unsigned)(recs[k] >> 24);
            }
        }
        __syncthreads();
    };

    // Pass 1: denominators (registers only, no atomics)
    float acc0 = 0.f, acc1 = 0.f;
    for (unsigned c = 0; c < nch; ++c) {
        sort_chunk(c);
        unsigned e0 = lst[dl], e1 = e0 + lh[dl];
        for (unsigned k = e0; k < e1; ++k) {
            float2 pv = *(const float2*)(p1 + (size_t)lsrc[k] * 8 + hp * 2);
            acc0 += __expf(lrelu(pv.x + p2a));
            acc1 += __expf(lrelu(pv.y + p2b));
        }
    }
    float r0 = 1.0f / (acc0 + 1e-16f);
    float r1 = 1.0f / (acc1 + 1e-16f);

    // Pass 2: outputs (chunk still LDS-resident when nch == 1)
    for (unsigned c = 0; c < nch; ++c) {
        if (nch > 1) sort_chunk(c);
        unsigned e0 = lst[dl], e1 = e0 + lh[dl];
        for (unsigned k = e0; k < e1; ++k) {
            unsigned src = lsrc[k], eid = leid[k];
            float2 pv = *(const float2*)(p1 + (size_t)src * 8 + hp * 2);
            floatx2 o;
            o.x = __expf(lrelu(pv.x + p2a)) * r0;
            o.y = __expf(lrelu(pv.y + p2b)) * r1;
            __builtin_nontemporal_store(o, (floatx2*)(out + (size_t)eid * 8 + hp * 2));
        }
    }
}

extern "C" void kernel_launch(void* const* d_in, const int* in_sizes, int n_in,
                              void* d_out, int out_size, void* d_ws, size_t ws_size,
                              hipStream_t stream) {
    const float* x    = (const float*)d_in[0];
    const float* a    = (const float*)d_in[1];
    const int*   edge = (const int*)d_in[2];
    float* out = (float*)d_out;

    // Workspace layout (~19.2 MB):
    unsigned long long* sorted = (unsigned long long*)d_ws;          // 12.8 MB
    float*    p1     = (float*)(sorted + N_EDGES);                   // 3.2 MB
    float*    p2     = p1 + NH;                                      // 3.2 MB
    unsigned* gcount = (unsigned*)(p2 + NH);                         // 782
    unsigned* goff   = gcount + NBUCK;                               // 783
    unsigned* gcur   = goff + NBUCK + 1;                             // 782

    (void)hipMemsetAsync(gcount, 0, NBUCK * sizeof(unsigned), stream);

    proj_hist_kernel<<<GPROJ + NEB, 1024, 0, stream>>>(x, a, edge, p1, p2, gcount);
    scan_kernel<<<1, 1024, 0, stream>>>(gcount, goff, gcur);
    scatter_kernel<<<NEB, 1024, 0, stream>>>(edge, gcur, sorted);
    fused_kernel<<<NBUCK, 512, 0, stream>>>(sorted, goff, p1, p2, out);
}